// Round 17
// baseline (334.084 us; speedup 1.0000x reference)
//
#include <hip/hip_runtime.h>
#include <cstddef>

#define H      128
#define NBATCH 32
#define NN     8192
#define RTOT   (NBATCH*NN) // 262144 rows
#define NLAYER 3
#define BNEPS  1e-5f
#define NSLOT  16
#define CNPB   128         // rows per conv tile (divides NN)
#define NTILEC (RTOT/CNPB) // 2048 conv tiles
#define HNPB   64          // rows per head tile
#define HS_STRIDE 136      // fp16 elems per LDS row (128 + 8 pad)

typedef _Float16 f16;
typedef __attribute__((ext_vector_type(8))) _Float16 half8;  // 8 fp16 (4 VGPRs)
typedef __attribute__((ext_vector_type(4))) float f32x4;     // MFMA C/D

__device__ __forceinline__ void unpackh8(uint4 pk, float* d) {
    const f16* hp = (const f16*)&pk;
    #pragma unroll
    for (int i = 0; i < 8; ++i) d[i] = (float)hp[i];
}
__device__ __forceinline__ uint4 packh8(const float* s) {
    uint4 pk;
    f16* hp = (f16*)&pk;
    #pragma unroll
    for (int i = 0; i < 8; ++i) hp[i] = (f16)s[i];
    return pk;
}

__device__ __forceinline__ void load_bfrags(
    const f16* __restrict__ Wt, half8 bW[2][4], int colbase, int l15, int quad)
{
    #pragma unroll
    for (int nt = 0; nt < 2; ++nt) {
        int nrow = colbase + nt * 16 + l15;
        #pragma unroll
        for (int ks = 0; ks < 4; ++ks)
            bW[nt][ks] = *((const half8*)(Wt + nrow * 128 + ks * 32 + quad * 8));
    }
}

// conv MFMA core over a 130-row hs tile: 128 out rows x 32 cols per wave
__device__ __forceinline__ void conv_mfma8(
    const f16* __restrict__ hs, const half8 bWl[2][4], const half8 bWn[2][4],
    f32x4 acc[8][2], int l15, int quad)
{
    #pragma unroll
    for (int mt = 0; mt < 8; ++mt) {
        acc[mt][0] = (f32x4){0.f, 0.f, 0.f, 0.f};
        acc[mt][1] = (f32x4){0.f, 0.f, 0.f, 0.f};
    }
    #pragma unroll
    for (int ks = 0; ks < 4; ++ks) {
        #pragma unroll
        for (int mt = 0; mt < 8; ++mt) {
            int row = mt * 16 + l15;
            const f16* base = hs + row * HS_STRIDE + ks * 32 + quad * 8;
            half8 hm = *((const half8*)(base + HS_STRIDE));       // center row
            half8 hd = *((const half8*)(base));                   // row-1
            half8 hu = *((const half8*)(base + 2 * HS_STRIDE));   // row+1
            half8 an = hd + hu;
            acc[mt][0] = __builtin_amdgcn_mfma_f32_16x16x32_f16(hm, bWl[0][ks], acc[mt][0], 0, 0, 0);
            acc[mt][1] = __builtin_amdgcn_mfma_f32_16x16x32_f16(hm, bWl[1][ks], acc[mt][1], 0, 0, 0);
            acc[mt][0] = __builtin_amdgcn_mfma_f32_16x16x32_f16(an, bWn[0][ks], acc[mt][0], 0, 0, 0);
            acc[mt][1] = __builtin_amdgcn_mfma_f32_16x16x32_f16(an, bWn[1][ks], acc[mt][1], 0, 0, 0);
        }
    }
}

// ---- weight prep: fp32 W[l][k][n] -> fp16 Wt[l][n][k] ----
__global__ __launch_bounds__(256) void k_prep(
    const float* __restrict__ lin_w, const float* __restrict__ nb_w,
    f16* __restrict__ Wlt, f16* __restrict__ Wnt)
{
    int id = blockIdx.x * 256 + threadIdx.x;
    int mat = id / 49152;
    int r   = id - mat * 49152;
    int l   = r >> 14;
    int r2  = r & 16383;
    int k   = r2 >> 7;
    int n   = r2 & 127;
    const float* src = mat ? nb_w : lin_w;
    f16*         dst = mat ? Wnt  : Wlt;
    dst[l * 16384 + n * 128 + k] = (f16)src[l * 16384 + k * 128 + n];
}

// ---- BN finalize helper ----
__device__ __forceinline__ void bn_finalize(
    const float* __restrict__ gstats, const float* __restrict__ bn_g,
    const float* __restrict__ bn_b, int t, float* scl_s, float* sft_s)
{
    if (t < H) {
        float s = 0.f, ss = 0.f;
        #pragma unroll
        for (int i = 0; i < NSLOT; ++i) {
            s  += gstats[i * 2 * H + t];
            ss += gstats[i * 2 * H + H + t];
        }
        const float invR = 1.f / (float)RTOT;
        float mean = s * invR;
        float var  = ss * invR - mean * mean;
        float inv  = rsqrtf(var + BNEPS);
        float sc   = bn_g[t] * inv;
        scl_s[t] = sc;
        sft_s[t] = fmaf(-mean, sc, bn_b[t]);
    }
}

// ---- DIRECT epilogue (big path): acc -> bias+mask -> scalar f16 row-major
//      global stores + BN stats atomics. No LDS use, no barriers. ----
__device__ __forceinline__ void conv_epilogue_d(
    f32x4 acc[8][2], const float bsum[2], const float* __restrict__ msk,
    f16* __restrict__ hnb, float* __restrict__ gstats,
    int r0, int colbase, int l15, int quad, int lane, int slot)
{
    float s[2] = {0.f, 0.f}, ss[2] = {0.f, 0.f};
    #pragma unroll
    for (int nt = 0; nt < 2; ++nt) {
        int col = colbase + nt * 16 + l15;
        #pragma unroll
        for (int mt = 0; mt < 8; ++mt)
            #pragma unroll
            for (int reg = 0; reg < 4; ++reg) {
                int lrow = mt * 16 + quad * 4 + reg;
                float v = (acc[mt][nt][reg] + bsum[nt]) * msk[lrow];
                hnb[(size_t)(r0 + lrow) * H + col] = (f16)v;
                s[nt] += v; ss[nt] += v * v;
            }
    }
    #pragma unroll
    for (int nt = 0; nt < 2; ++nt) {
        s[nt]  += __shfl_xor(s[nt], 16);  s[nt]  += __shfl_xor(s[nt], 32);
        ss[nt] += __shfl_xor(ss[nt], 16); ss[nt] += __shfl_xor(ss[nt], 32);
    }
    if (lane < 16)
        #pragma unroll
        for (int nt = 0; nt < 2; ++nt) {
            int col = colbase + nt * 16 + lane;
            atomicAdd(&gstats[slot * 2 * H + col],     s[nt]);
            atomicAdd(&gstats[slot * 2 * H + H + col], ss[nt]);
        }
}

// =================== C-layout epilogue + norm path (small path, proven) ===================
__device__ __forceinline__ void conv_epilogue_c(
    f32x4 acc[8][2], const float bsum[2], const float* __restrict__ msk,
    f16* __restrict__ hnb, float* __restrict__ gstats,
    int tile, int wave, int quad, int lane, int slot)
{
    uint2* out2 = (uint2*)hnb;
    float s[2] = {0.f, 0.f}, ss[2] = {0.f, 0.f};
    #pragma unroll
    for (int nt = 0; nt < 2; ++nt) {
        #pragma unroll
        for (int mt = 0; mt < 8; ++mt) {
            f16 v4[4];
            #pragma unroll
            for (int reg = 0; reg < 4; ++reg) {
                int lrow = mt * 16 + quad * 4 + reg;
                float v = (acc[mt][nt][reg] + bsum[nt]) * msk[lrow];
                v4[reg] = (f16)v;
                s[nt] += v; ss[nt] += v * v;
            }
            size_t chunk = ((size_t)tile * 4 + wave) * 16 + mt * 2 + nt;
            out2[chunk * 64 + lane] = *((const uint2*)v4);
        }
    }
    #pragma unroll
    for (int nt = 0; nt < 2; ++nt) {
        s[nt]  += __shfl_xor(s[nt], 16);  s[nt]  += __shfl_xor(s[nt], 32);
        ss[nt] += __shfl_xor(ss[nt], 16); ss[nt] += __shfl_xor(ss[nt], 32);
    }
    if (lane < 16) {
        int colbase = wave * 32;
        #pragma unroll
        for (int nt = 0; nt < 2; ++nt) {
            int col = colbase + nt * 16 + lane;
            atomicAdd(&gstats[slot * 2 * H + col],     s[nt]);
            atomicAdd(&gstats[slot * 2 * H + H + col], ss[nt]);
        }
    }
}

// ---- layer 0 conv (C-layout variant, small path) ----
__global__ __launch_bounds__(256) void k_conv0f(
    const float* __restrict__ x, const float* __restrict__ ew,
    const float* __restrict__ eb,
    const f16* __restrict__ Wlt, const f16* __restrict__ Wnt,
    const float* __restrict__ bl, const float* __restrict__ bnb,
    const float* __restrict__ mask,
    f16* __restrict__ hnb, float* __restrict__ gstats)
{
    __shared__ __align__(16) f16 hs[(CNPB + 2) * HS_STRIDE];
    __shared__ float ews[3 * H], msk[CNPB];
    const int t = threadIdx.x, lane = t & 63;
    const int l15 = lane & 15, quad = lane >> 4;
    const int wave = t >> 6;
    const int colbase = wave * 32;
    const int r0 = blockIdx.x * CNPB;
    const int batch = r0 >> 13, n0 = r0 & (NN - 1);

    half8 bWl[2][4], bWn[2][4];
    load_bfrags(Wlt, bWl, colbase, l15, quad);
    load_bfrags(Wnt, bWn, colbase, l15, quad);
    float bsum[2];
    #pragma unroll
    for (int nt = 0; nt < 2; ++nt) {
        int col = colbase + nt * 16 + l15;
        bsum[nt] = bl[col] + bnb[col];
    }
    for (int c = t; c < H; c += 256) {
        ews[c] = ew[c]; ews[H + c] = ew[H + c]; ews[2 * H + c] = eb[c];
    }
    if (t < CNPB) msk[t] = mask[r0 + t];
    __syncthreads();

    for (int i = t; i < (CNPB + 2) * 16; i += 256) {
        int row = i >> 4, g = i & 15;
        int n = (n0 + row - 1 + NN) & (NN - 1);
        const float* xp = x + 2 * ((size_t)batch * NN + n);
        float x0 = xp[0], x1 = xp[1];
        f16 o[8];
        #pragma unroll
        for (int e = 0; e < 8; ++e) {
            int c = g * 8 + e;
            o[e] = (f16)fmaf(x1, ews[H + c], fmaf(x0, ews[c], ews[2 * H + c]));
        }
        *((uint4*)(hs + row * HS_STRIDE + g * 8)) = *((const uint4*)o);
    }
    __syncthreads();

    f32x4 acc[8][2];
    conv_mfma8(hs, bWl, bWn, acc, l15, quad);
    conv_epilogue_c(acc, bsum, msk, hnb, gstats,
                    blockIdx.x, wave, quad, lane, blockIdx.x & (NSLOT - 1));
}

// ---- layer 0 conv (direct-store variant, big path) ----
__global__ __launch_bounds__(256) void k_conv0f_rm(
    const float* __restrict__ x, const float* __restrict__ ew,
    const float* __restrict__ eb,
    const f16* __restrict__ Wlt, const f16* __restrict__ Wnt,
    const float* __restrict__ bl, const float* __restrict__ bnb,
    const float* __restrict__ mask,
    f16* __restrict__ hnb, float* __restrict__ gstats)
{
    __shared__ __align__(16) f16 hs[(CNPB + 2) * HS_STRIDE];
    __shared__ float ews[3 * H], msk[CNPB];
    const int t = threadIdx.x, lane = t & 63;
    const int l15 = lane & 15, quad = lane >> 4;
    const int wave = t >> 6;
    const int colbase = wave * 32;
    const int r0 = blockIdx.x * CNPB;
    const int batch = r0 >> 13, n0 = r0 & (NN - 1);

    half8 bWl[2][4], bWn[2][4];
    load_bfrags(Wlt, bWl, colbase, l15, quad);
    load_bfrags(Wnt, bWn, colbase, l15, quad);
    float bsum[2];
    #pragma unroll
    for (int nt = 0; nt < 2; ++nt) {
        int col = colbase + nt * 16 + l15;
        bsum[nt] = bl[col] + bnb[col];
    }
    for (int c = t; c < H; c += 256) {
        ews[c] = ew[c]; ews[H + c] = ew[H + c]; ews[2 * H + c] = eb[c];
    }
    if (t < CNPB) msk[t] = mask[r0 + t];
    __syncthreads();

    for (int i = t; i < (CNPB + 2) * 16; i += 256) {
        int row = i >> 4, g = i & 15;
        int n = (n0 + row - 1 + NN) & (NN - 1);
        const float* xp = x + 2 * ((size_t)batch * NN + n);
        float x0 = xp[0], x1 = xp[1];
        f16 o[8];
        #pragma unroll
        for (int e = 0; e < 8; ++e) {
            int c = g * 8 + e;
            o[e] = (f16)fmaf(x1, ews[H + c], fmaf(x0, ews[c], ews[2 * H + c]));
        }
        *((uint4*)(hs + row * HS_STRIDE + g * 8)) = *((const uint4*)o);
    }
    __syncthreads();

    f32x4 acc[8][2];
    conv_mfma8(hs, bWl, bWn, acc, l15, quad);
    conv_epilogue_d(acc, bsum, msk, hnb, gstats,
                    r0, colbase, l15, quad, lane, blockIdx.x & (NSLOT - 1));
}

// ---- generic conv (layers 1,2; C-layout, small path) ----
__global__ __launch_bounds__(256) void k_conv(
    const f16* __restrict__ hb,
    const f16* __restrict__ Wlt, const f16* __restrict__ Wnt,
    const float* __restrict__ bl, const float* __restrict__ bnb,
    const float* __restrict__ mask,
    f16* __restrict__ hnb, float* __restrict__ gstats)
{
    __shared__ __align__(16) f16 hs[(CNPB + 2) * HS_STRIDE];
    __shared__ float msk[CNPB];
    const int t = threadIdx.x, lane = t & 63;
    const int l15 = lane & 15, quad = lane >> 4;
    const int wave = t >> 6;
    const int colbase = wave * 32;
    const int r0 = blockIdx.x * CNPB;
    const int batch = r0 >> 13, n0 = r0 & (NN - 1);

    half8 bWl[2][4], bWn[2][4];
    load_bfrags(Wlt, bWl, colbase, l15, quad);
    load_bfrags(Wnt, bWn, colbase, l15, quad);
    float bsum[2];
    #pragma unroll
    for (int nt = 0; nt < 2; ++nt) {
        int col = colbase + nt * 16 + l15;
        bsum[nt] = bl[col] + bnb[col];
    }
    if (t < CNPB) msk[t] = mask[r0 + t];

    for (int i = t; i < (CNPB + 2) * 16; i += 256) {
        int row = i >> 4, g = i & 15;
        int n = (n0 + row - 1 + NN) & (NN - 1);
        *((uint4*)(hs + row * HS_STRIDE + g * 8)) =
            *((const uint4*)(hb + ((size_t)(batch * NN + n)) * H + g * 8));
    }
    __syncthreads();

    f32x4 acc[8][2];
    conv_mfma8(hs, bWl, bWn, acc, l15, quad);
    conv_epilogue_c(acc, bsum, msk, hnb, gstats,
                    blockIdx.x, wave, quad, lane, blockIdx.x & (NSLOT - 1));
}

// ---- fused conv layer 1 (big path): h1 = affine(x)+relu(BN0(hn0));
//      BN0 per block; HB written during staging; direct-store epilogue ----
__global__ __launch_bounds__(256, 3) void k_cn1(
    const float* __restrict__ x, const float* __restrict__ ew,
    const float* __restrict__ eb, const f16* __restrict__ hnA,
    const float* __restrict__ gst0, const float* __restrict__ bn_g,
    const float* __restrict__ bn_b,
    const f16* __restrict__ Wlt, const f16* __restrict__ Wnt,
    const float* __restrict__ bl, const float* __restrict__ bnb,
    const float* __restrict__ mask,
    f16* __restrict__ HB, f16* __restrict__ hnB, float* __restrict__ gst1)
{
    __shared__ __align__(16) f16 hs[(CNPB + 2) * HS_STRIDE];
    __shared__ float ews[3 * H], sclA[H], sftA[H], msk[CNPB];
    const int t = threadIdx.x, lane = t & 63;
    const int l15 = lane & 15, quad = lane >> 4;
    const int wave = t >> 6;
    const int colbase = wave * 32;
    const int r0 = blockIdx.x * CNPB;
    const int batch = r0 >> 13, n0 = r0 & (NN - 1);

    half8 bWl[2][4], bWn[2][4];
    load_bfrags(Wlt, bWl, colbase, l15, quad);
    load_bfrags(Wnt, bWn, colbase, l15, quad);
    float bsum[2];
    #pragma unroll
    for (int nt = 0; nt < 2; ++nt) {
        int col = colbase + nt * 16 + l15;
        bsum[nt] = bl[col] + bnb[col];
    }
    bn_finalize(gst0, bn_g, bn_b, t, sclA, sftA);
    for (int c = t; c < H; c += 256) {
        ews[c] = ew[c]; ews[H + c] = ew[H + c]; ews[2 * H + c] = eb[c];
    }
    if (t < CNPB) msk[t] = mask[r0 + t];
    __syncthreads();

    for (int i = t; i < (CNPB + 2) * 16; i += 256) {
        int row = i >> 4, g = i & 15;
        int n = (n0 + row - 1 + NN) & (NN - 1);
        size_t base = (size_t)batch * NN + n;
        const float* xp = x + 2 * base;
        float x0 = xp[0], x1 = xp[1];
        uint4 pa = *((const uint4*)(hnA + base * H + g * 8));
        float va[8];
        unpackh8(pa, va);
        f16 o[8];
        #pragma unroll
        for (int e = 0; e < 8; ++e) {
            int c = g * 8 + e;
            float h0 = fmaf(x1, ews[H + c], fmaf(x0, ews[c], ews[2 * H + c]));
            o[e] = (f16)(h0 + fmaxf(fmaf(va[e], sclA[c], sftA[c]), 0.f));
        }
        *((uint4*)(hs + row * HS_STRIDE + g * 8)) = *((const uint4*)o);
        if (row >= 1 && row <= CNPB)   // h1 tile rows -> HB (own-row, exact once)
            *((uint4*)(HB + base * H + g * 8)) = *((const uint4*)o);
    }
    __syncthreads();

    f32x4 acc[8][2];
    conv_mfma8(hs, bWl, bWn, acc, l15, quad);
    conv_epilogue_d(acc, bsum, msk, hnB, gst1,
                    r0, colbase, l15, quad, lane, blockIdx.x & (NSLOT - 1));
}

// ---- fused conv layer 2 (big path): h2 = h1 + relu(BN1(hn1)); direct-store ----
__global__ __launch_bounds__(256) void k_cn2(
    const f16* __restrict__ HB, const f16* __restrict__ hnB,
    const float* __restrict__ gst1, const float* __restrict__ bn_g,
    const float* __restrict__ bn_b,
    const f16* __restrict__ Wlt, const f16* __restrict__ Wnt,
    const float* __restrict__ bl, const float* __restrict__ bnb,
    const float* __restrict__ mask,
    f16* __restrict__ hnA, float* __restrict__ gst2)
{
    __shared__ __align__(16) f16 hs[(CNPB + 2) * HS_STRIDE];
    __shared__ float sclA[H], sftA[H], msk[CNPB];
    const int t = threadIdx.x, lane = t & 63;
    const int l15 = lane & 15, quad = lane >> 4;
    const int wave = t >> 6;
    const int colbase = wave * 32;
    const int r0 = blockIdx.x * CNPB;
    const int batch = r0 >> 13, n0 = r0 & (NN - 1);

    half8 bWl[2][4], bWn[2][4];
    load_bfrags(Wlt, bWl, colbase, l15, quad);
    load_bfrags(Wnt, bWn, colbase, l15, quad);
    float bsum[2];
    #pragma unroll
    for (int nt = 0; nt < 2; ++nt) {
        int col = colbase + nt * 16 + l15;
        bsum[nt] = bl[col] + bnb[col];
    }
    bn_finalize(gst1, bn_g, bn_b, t, sclA, sftA);
    if (t < CNPB) msk[t] = mask[r0 + t];
    __syncthreads();

    for (int i = t; i < (CNPB + 2) * 16; i += 256) {
        int row = i >> 4, g = i & 15;
        int n = (n0 + row - 1 + NN) & (NN - 1);
        size_t off = ((size_t)batch * NN + n) * H + g * 8;
        uint4 ph = *((const uint4*)(HB + off));
        uint4 pn = *((const uint4*)(hnB + off));
        float vh[8], vn[8];
        unpackh8(ph, vh);
        unpackh8(pn, vn);
        f16 o[8];
        #pragma unroll
        for (int e = 0; e < 8; ++e) {
            int c = g * 8 + e;
            o[e] = (f16)(vh[e] + fmaxf(fmaf(vn[e], sclA[c], sftA[c]), 0.f));
        }
        *((uint4*)(hs + row * HS_STRIDE + g * 8)) = *((const uint4*)o);
    }
    __syncthreads();

    f32x4 acc[8][2];
    conv_mfma8(hs, bWl, bWn, acc, l15, quad);
    conv_epilogue_d(acc, bsum, msk, hnA, gst2,
                    r0, colbase, l15, quad, lane, blockIdx.x & (NSLOT - 1));
}

// =================== small-path norm kernels (R13, proven) ===================
__device__ __forceinline__ void norm_ingest(
    const f16* __restrict__ hnb, int blk, int t,
    const float* __restrict__ scl_s, const float* __restrict__ sft_s,
    f16* __restrict__ g)
{
    const uint4* src = (const uint4*)hnb + (size_t)blk * 2048;
    for (int i = t; i < 2048; i += 256) {
        uint4 pk = src[i];
        int chunk = i >> 5;
        int L     = (i & 31) * 2;
        int ntv   = chunk & 1;
        int mtv   = (chunk >> 1) & 7;
        int wv    = chunk >> 4;
        int c0    = wv * 32 + ntv * 16 + (L & 15);
        int row0  = mtv * 16 + (L >> 4) * 4;
        float vv[8];
        unpackh8(pk, vv);
        #pragma unroll
        for (int e = 0; e < 8; ++e) {
            int cc = c0 + (e >> 2);
            int rr = row0 + (e & 3);
            float q = fmaxf(fmaf(vv[e], scl_s[cc], sft_s[cc]), 0.f);
            g[rr * HS_STRIDE + cc] = (f16)q;
        }
    }
}

__global__ __launch_bounds__(256) void k_norm0(
    const float* __restrict__ x, const float* __restrict__ ew,
    const float* __restrict__ eb, const f16* __restrict__ hnb,
    const float* __restrict__ gstats, const float* __restrict__ bn_g,
    const float* __restrict__ bn_b, f16* __restrict__ hb)
{
    __shared__ __align__(16) f16 g[CNPB * HS_STRIDE];
    __shared__ float scl_s[H], sft_s[H], ews[3 * H];
    const int t = threadIdx.x;
    const int blk = blockIdx.x;
    const size_t r0 = (size_t)blk * CNPB;

    bn_finalize(gstats, bn_g, bn_b, t, scl_s, sft_s);
    if (t < H) { ews[t] = ew[t]; ews[H + t] = ew[H + t]; ews[2 * H + t] = eb[t]; }
    __syncthreads();

    norm_ingest(hnb, blk, t, scl_s, sft_s, g);
    __syncthreads();

    for (int i = t; i < 2048; i += 256) {
        int row = i >> 4, gg = i & 15;
        size_t grow = r0 + row;
        float x0 = x[2 * grow], x1 = x[2 * grow + 1];
        uint4 pg = *((const uint4*)(g + row * HS_STRIDE + gg * 8));
        float vg[8], vh[8];
        unpackh8(pg, vg);
        #pragma unroll
        for (int e = 0; e < 8; ++e) {
            int c = gg * 8 + e;
            float h0 = fmaf(x1, ews[H + c], fmaf(x0, ews[c], ews[2 * H + c]));
            vh[e] = h0 + vg[e];
        }
        *((uint4*)(hb + grow * H + gg * 8)) = packh8(vh);
    }
}

__global__ __launch_bounds__(256) void k_norm(
    const f16* __restrict__ hnb, const float* __restrict__ gstats,
    const float* __restrict__ bn_g, const float* __restrict__ bn_b,
    f16* __restrict__ hb)
{
    __shared__ __align__(16) f16 g[CNPB * HS_STRIDE];
    __shared__ float scl_s[H], sft_s[H];
    const int t = threadIdx.x;
    const int blk = blockIdx.x;
    const size_t r0 = (size_t)blk * CNPB;

    bn_finalize(gstats, bn_g, bn_b, t, scl_s, sft_s);
    __syncthreads();

    norm_ingest(hnb, blk, t, scl_s, sft_s, g);
    __syncthreads();

    for (int i = t; i < 2048; i += 256) {
        int row = i >> 4, gg = i & 15;
        size_t grow = r0 + row;
        uint4 ph = *((const uint4*)(hb + grow * H + gg * 8));
        uint4 pg = *((const uint4*)(g + row * HS_STRIDE + gg * 8));
        float vh[8], vg[8];
        unpackh8(ph, vh);
        unpackh8(pg, vg);
        #pragma unroll
        for (int e = 0; e < 8; ++e) vh[e] += vg[e];
        *((uint4*)(hb + grow * H + gg * 8)) = packh8(vh);
    }
}

// ---- MFMA head (small path, R13) ----
__global__ __launch_bounds__(256) void k_head(
    const f16* __restrict__ hb, const float* __restrict__ W1,
    const float* __restrict__ b1, const float* __restrict__ W2,
    const float* __restrict__ b2, const float* __restrict__ mask,
    float* __restrict__ out)
{
    __shared__ f16 hs [64 * HS_STRIDE];
    __shared__ f16 w1t[64 * HS_STRIDE];
    const int t    = threadIdx.x;
    const int wave = t >> 6;
    const int lane = t & 63;
    const int l15  = lane & 15;
    const int quad = lane >> 4;
    const int r0   = blockIdx.x * HNPB;

    for (int i = t; i < 64 * 16; i += 256) {
        int row = i >> 4, g = i & 15;
        *((uint4*)(hs + row * HS_STRIDE + g * 8)) =
            *((const uint4*)(hb + (size_t)(r0 + row) * H + g * 8));
    }
    for (int i = t; i < H * 64; i += 256) {
        int k = i >> 6, n = i & 63;
        w1t[n * HS_STRIDE + k] = (f16)W1[i];
    }
    __syncthreads();

    f32x4 acc[4];
    #pragma unroll
    for (int nt = 0; nt < 4; ++nt) acc[nt] = (f32x4){0.f, 0.f, 0.f, 0.f};
    #pragma unroll
    for (int ks = 0; ks < 4; ++ks) {
        half8 a = *((const half8*)(hs + (wave * 16 + l15) * HS_STRIDE + ks * 32 + quad * 8));
        #pragma unroll
        for (int nt = 0; nt < 4; ++nt) {
            half8 b = *((const half8*)(w1t + (nt * 16 + l15) * HS_STRIDE + ks * 32 + quad * 8));
            acc[nt] = __builtin_amdgcn_mfma_f32_16x16x32_f16(a, b, acc[nt], 0, 0, 0);
        }
    }

    float p0[4] = {0,0,0,0}, p1[4] = {0,0,0,0};
    #pragma unroll
    for (int nt = 0; nt < 4; ++nt) {
        int col = nt * 16 + l15;
        float bb = b1[col];
        float wa = W2[2 * col], wb = W2[2 * col + 1];
        #pragma unroll
        for (int reg = 0; reg < 4; ++reg) {
            float v = fmaxf(acc[nt][reg] + bb, 0.f);
            p0[reg] = fmaf(v, wa, p0[reg]);
            p1[reg] = fmaf(v, wb, p1[reg]);
        }
    }
    #pragma unroll
    for (int reg = 0; reg < 4; ++reg) {
        p0[reg] += __shfl_xor(p0[reg], 1); p0[reg] += __shfl_xor(p0[reg], 2);
        p0[reg] += __shfl_xor(p0[reg], 4); p0[reg] += __shfl_xor(p0[reg], 8);
        p1[reg] += __shfl_xor(p1[reg], 1); p1[reg] += __shfl_xor(p1[reg], 2);
        p1[reg] += __shfl_xor(p1[reg], 4); p1[reg] += __shfl_xor(p1[reg], 8);
    }
    if (l15 == 0) {
        #pragma unroll
        for (int reg = 0; reg < 4; ++reg) {
            int gr = r0 + wave * 16 + quad * 4 + reg;
            float m = mask[gr];
            float2 o;
            o.x = (p0[reg] + b2[0]) * m;
            o.y = (p1[reg] + b2[1]) * m;
            *((float2*)(out + 2 * gr)) = o;
        }
    }
}

// ---- fused head (big path): h3 chain; BN per block from WS gstats ----
// Invariant: this kernel writes `out` (d_out) and reads NOTHING from d_out.
__global__ __launch_bounds__(256) void k_head_f(
    const f16* __restrict__ HB, const f16* __restrict__ hn1,
    const f16* __restrict__ hn2,
    const float* __restrict__ gst1, const float* __restrict__ gst2,
    const float* __restrict__ bn_g, const float* __restrict__ bn_b,
    const float* __restrict__ W1, const float* __restrict__ b1,
    const float* __restrict__ W2, const float* __restrict__ b2,
    const float* __restrict__ mask, float* __restrict__ out)
{
    __shared__ f16 hs [64 * HS_STRIDE];
    __shared__ f16 w1t[64 * HS_STRIDE];
    __shared__ float scl1[H], sft1[H], scl2[H], sft2[H];
    const int t    = threadIdx.x;
    const int wave = t >> 6;
    const int lane = t & 63;
    const int l15  = lane & 15;
    const int quad = lane >> 4;
    const int r0   = blockIdx.x * HNPB;

    bn_finalize(gst1, bn_g,     bn_b,     t, scl1, sft1);
    bn_finalize(gst2, bn_g + H, bn_b + H, t, scl2, sft2);
    for (int i = t; i < H * 64; i += 256) {
        int k = i >> 6, n = i & 63;
        w1t[n * HS_STRIDE + k] = (f16)W1[i];
    }
    __syncthreads();   // scl ready for compose

    for (int i = t; i < 64 * 16; i += 256) {
        int row = i >> 4, g = i & 15;
        size_t off = (size_t)(r0 + row) * H + g * 8;
        uint4 ph = *((const uint4*)(HB + off));
        uint4 p1v = *((const uint4*)(hn1 + off));
        uint4 p2v = *((const uint4*)(hn2 + off));
        float vh[8], v1[8], v2[8];
        unpackh8(ph, vh);
        unpackh8(p1v, v1);
        unpackh8(p2v, v2);
        f16 o[8];
        #pragma unroll
        for (int e = 0; e < 8; ++e) {
            int c = g * 8 + e;
            float h2 = vh[e] + fmaxf(fmaf(v1[e], scl1[c], sft1[c]), 0.f);
            o[e] = (f16)(h2 + fmaxf(fmaf(v2[e], scl2[c], sft2[c]), 0.f));
        }
        *((uint4*)(hs + row * HS_STRIDE + g * 8)) = *((const uint4*)o);
    }
    __syncthreads();

    f32x4 acc[4];
    #pragma unroll
    for (int nt = 0; nt < 4; ++nt) acc[nt] = (f32x4){0.f, 0.f, 0.f, 0.f};
    #pragma unroll
    for (int ks = 0; ks < 4; ++ks) {
        half8 a = *((const half8*)(hs + (wave * 16 + l15) * HS_STRIDE + ks * 32 + quad * 8));
        #pragma unroll
        for (int nt = 0; nt < 4; ++nt) {
            half8 b = *((const half8*)(w1t + (nt * 16 + l15) * HS_STRIDE + ks * 32 + quad * 8));
            acc[nt] = __builtin_amdgcn_mfma_f32_16x16x32_f16(a, b, acc[nt], 0, 0, 0);
        }
    }

    float p0[4] = {0,0,0,0}, p1a[4] = {0,0,0,0};
    #pragma unroll
    for (int nt = 0; nt < 4; ++nt) {
        int col = nt * 16 + l15;
        float bb = b1[col];
        float wa = W2[2 * col], wb = W2[2 * col + 1];
        #pragma unroll
        for (int reg = 0; reg < 4; ++reg) {
            float v = fmaxf(acc[nt][reg] + bb, 0.f);
            p0[reg]  = fmaf(v, wa, p0[reg]);
            p1a[reg] = fmaf(v, wb, p1a[reg]);
        }
    }
    #pragma unroll
    for (int reg = 0; reg < 4; ++reg) {
        p0[reg]  += __shfl_xor(p0[reg], 1);  p0[reg]  += __shfl_xor(p0[reg], 2);
        p0[reg]  += __shfl_xor(p0[reg], 4);  p0[reg]  += __shfl_xor(p0[reg], 8);
        p1a[reg] += __shfl_xor(p1a[reg], 1); p1a[reg] += __shfl_xor(p1a[reg], 2);
        p1a[reg] += __shfl_xor(p1a[reg], 4); p1a[reg] += __shfl_xor(p1a[reg], 8);
    }
    if (l15 == 0) {
        #pragma unroll
        for (int reg = 0; reg < 4; ++reg) {
            int gr = r0 + wave * 16 + quad * 4 + reg;
            float m = mask[gr];
            float2 o;
            o.x = (p0[reg]  + b2[0]) * m;
            o.y = (p1a[reg] + b2[1]) * m;
            *((float2*)(out + 2 * gr)) = o;
        }
    }
}

extern "C" void kernel_launch(void* const* d_in, const int* in_sizes, int n_in,
                              void* d_out, int out_size, void* d_ws, size_t ws_size,
                              hipStream_t stream)
{
    const float* x     = (const float*)d_in[0];
    const float* mask  = (const float*)d_in[1];
    const float* emb_w = (const float*)d_in[2];
    const float* emb_b = (const float*)d_in[3];
    const float* lin_w = (const float*)d_in[4];
    const float* lin_b = (const float*)d_in[5];
    const float* nb_w  = (const float*)d_in[6];
    const float* nb_b  = (const float*)d_in[7];
    const float* bn_g  = (const float*)d_in[8];
    const float* bn_b  = (const float*)d_in[9];
    const float* o1w   = (const float*)d_in[10];
    const float* o1b   = (const float*)d_in[11];
    const float* o2w   = (const float*)d_in[12];
    const float* o2b   = (const float*)d_in[13];
    float* out = (float*)d_out;

    const size_t BUF = (size_t)RTOT * H * 2;   // 64 MiB per f16 buffer
    const size_t GSTB = NLAYER * NSLOT * 2 * H * sizeof(float);  // 48 KiB
    char* ws = (char*)d_ws;

    // d_out holds ONLY Wlt/Wnt (read by conv kernels that never write `out`).
    f16* Wlt = (f16*)((float*)d_out + 65536);    // 3*128*128 fp16
    f16* Wnt = Wlt + NLAYER * H * H;
    k_prep<<<384, 256, 0, stream>>>(lin_w, nb_w, Wlt, Wnt);

    if (ws_size >= 3 * BUF + 65536) {
        // ---- big path: 3 data buffers + gstats all in WS ----
        f16* HB  = (f16*)ws;
        f16* hnA = (f16*)(ws + BUF);
        f16* hnB = (f16*)(ws + 2 * BUF);
        float* gstw = (float*)(ws + 3 * BUF);    // 3 layers of gstats (48 KiB)

        hipMemsetAsync(gstw, 0, GSTB, stream);

        k_conv0f_rm<<<NTILEC, 256, 0, stream>>>(
            x, emb_w, emb_b, Wlt, Wnt, lin_b, nb_b, mask, hnA, gstw);
        k_cn1<<<NTILEC, 256, 0, stream>>>(
            x, emb_w, emb_b, hnA, gstw, bn_g, bn_b, Wlt + H * H, Wnt + H * H,
            lin_b + H, nb_b + H, mask, HB, hnB, gstw + NSLOT * 2 * H);
        k_cn2<<<NTILEC, 256, 0, stream>>>(
            HB, hnB, gstw + NSLOT * 2 * H, bn_g + H, bn_b + H,
            Wlt + 2 * H * H, Wnt + 2 * H * H,
            lin_b + 2 * H, nb_b + 2 * H, mask, hnA, gstw + 2 * NSLOT * 2 * H);
        k_head_f<<<RTOT / HNPB, 256, 0, stream>>>(
            HB, hnB, hnA, gstw + NSLOT * 2 * H, gstw + 2 * NSLOT * 2 * H,
            bn_g + H, bn_b + H, o1w, o1b, o2w, o2b, mask, out);
    } else {
        // ---- small path: exact R13 pipeline (proven, 343.6 us) ----
        float* gst = (float*)d_out;   // safe here: k_head reads no d_out scratch
        f16* hb  = (f16*)ws;
        f16* hnb = (f16*)(ws + BUF);

        hipMemsetAsync(gst, 0, GSTB, stream);

        k_conv0f<<<NTILEC, 256, 0, stream>>>(
            x, emb_w, emb_b, Wlt, Wnt, lin_b, nb_b, mask, hnb, gst);
        k_norm0<<<NTILEC, 256, 0, stream>>>(
            x, emb_w, emb_b, hnb, gst, bn_g, bn_b, hb);
        for (int i = 1; i < NLAYER; ++i) {
            k_conv<<<NTILEC, 256, 0, stream>>>(
                hb, Wlt + i * H * H, Wnt + i * H * H,
                lin_b + i * H, nb_b + i * H, mask,
                hnb, gst + i * NSLOT * 2 * H);
            k_norm<<<NTILEC, 256, 0, stream>>>(
                hnb, gst + i * NSLOT * 2 * H, bn_g + i * H, bn_b + i * H, hb);
        }
        k_head<<<RTOT / HNPB, 256, 0, stream>>>(hb, o1w, o1b, o2w, o2b, mask, out);
    }
}

// Round 19
// 284.969 us; speedup vs baseline: 1.1724x; 1.1724x over previous
//
#include <hip/hip_runtime.h>
#include <cstddef>

#define H      128
#define NBATCH 32
#define NN     8192
#define RTOT   (NBATCH*NN) // 262144 rows
#define NLAYER 3
#define BNEPS  1e-5f
#define NSLOT  16
#define CNPB   128         // rows per conv tile (divides NN)
#define NTILEC (RTOT/CNPB) // 2048 conv tiles
#define HNPB   64          // rows per head tile
#define HS_STRIDE 136      // fp16 elems per LDS row (128 + 8 pad)

typedef _Float16 f16;
typedef __attribute__((ext_vector_type(8))) _Float16 half8;  // 8 fp16 (4 VGPRs)
typedef __attribute__((ext_vector_type(4))) float f32x4;     // MFMA C/D

__device__ __forceinline__ void unpackh8(uint4 pk, float* d) {
    const f16* hp = (const f16*)&pk;
    #pragma unroll
    for (int i = 0; i < 8; ++i) d[i] = (float)hp[i];
}
__device__ __forceinline__ uint4 packh8(const float* s) {
    uint4 pk;
    f16* hp = (f16*)&pk;
    #pragma unroll
    for (int i = 0; i < 8; ++i) hp[i] = (f16)s[i];
    return pk;
}

__device__ __forceinline__ void load_bfrags(
    const f16* __restrict__ Wt, half8 bW[2][4], int colbase, int l15, int quad)
{
    #pragma unroll
    for (int nt = 0; nt < 2; ++nt) {
        int nrow = colbase + nt * 16 + l15;
        #pragma unroll
        for (int ks = 0; ks < 4; ++ks)
            bW[nt][ks] = *((const half8*)(Wt + nrow * 128 + ks * 32 + quad * 8));
    }
}

// conv MFMA core over a 130-row hs tile: 128 out rows x 32 cols per wave
__device__ __forceinline__ void conv_mfma8(
    const f16* __restrict__ hs, const half8 bWl[2][4], const half8 bWn[2][4],
    f32x4 acc[8][2], int l15, int quad)
{
    #pragma unroll
    for (int mt = 0; mt < 8; ++mt) {
        acc[mt][0] = (f32x4){0.f, 0.f, 0.f, 0.f};
        acc[mt][1] = (f32x4){0.f, 0.f, 0.f, 0.f};
    }
    #pragma unroll
    for (int ks = 0; ks < 4; ++ks) {
        #pragma unroll
        for (int mt = 0; mt < 8; ++mt) {
            int row = mt * 16 + l15;
            const f16* base = hs + row * HS_STRIDE + ks * 32 + quad * 8;
            half8 hm = *((const half8*)(base + HS_STRIDE));       // center row
            half8 hd = *((const half8*)(base));                   // row-1
            half8 hu = *((const half8*)(base + 2 * HS_STRIDE));   // row+1
            half8 an = hd + hu;
            acc[mt][0] = __builtin_amdgcn_mfma_f32_16x16x32_f16(hm, bWl[0][ks], acc[mt][0], 0, 0, 0);
            acc[mt][1] = __builtin_amdgcn_mfma_f32_16x16x32_f16(hm, bWl[1][ks], acc[mt][1], 0, 0, 0);
            acc[mt][0] = __builtin_amdgcn_mfma_f32_16x16x32_f16(an, bWn[0][ks], acc[mt][0], 0, 0, 0);
            acc[mt][1] = __builtin_amdgcn_mfma_f32_16x16x32_f16(an, bWn[1][ks], acc[mt][1], 0, 0, 0);
        }
    }
}

// ---- weight prep: fp32 W[l][k][n] -> fp16 Wt[l][n][k]; optional W1 -> W1t ----
__global__ __launch_bounds__(256) void k_prep(
    const float* __restrict__ lin_w, const float* __restrict__ nb_w,
    const float* __restrict__ o1w,
    f16* __restrict__ Wlt, f16* __restrict__ Wnt, f16* __restrict__ W1t)
{
    int id = blockIdx.x * 256 + threadIdx.x;
    if (id >= 98304) {                 // W1 [128][64] -> W1t [n=64][k=128] fp16
        if (W1t) {
            int r = id - 98304;        // 0..8191
            if (r < 8192) {
                int k = r >> 6, n = r & 63;
                W1t[n * 128 + k] = (f16)o1w[k * 64 + n];
            }
        }
        return;
    }
    int mat = id / 49152;
    int r   = id - mat * 49152;
    int l   = r >> 14;
    int r2  = r & 16383;
    int k   = r2 >> 7;
    int n   = r2 & 127;
    const float* src = mat ? nb_w : lin_w;
    f16*         dst = mat ? Wnt  : Wlt;
    dst[l * 16384 + n * 128 + k] = (f16)src[l * 16384 + k * 128 + n];
}

// ---- BN finalize helper ----
__device__ __forceinline__ void bn_finalize(
    const float* __restrict__ gstats, const float* __restrict__ bn_g,
    const float* __restrict__ bn_b, int t, float* scl_s, float* sft_s)
{
    if (t < H) {
        float s = 0.f, ss = 0.f;
        #pragma unroll
        for (int i = 0; i < NSLOT; ++i) {
            s  += gstats[i * 2 * H + t];
            ss += gstats[i * 2 * H + H + t];
        }
        const float invR = 1.f / (float)RTOT;
        float mean = s * invR;
        float var  = ss * invR - mean * mean;
        float inv  = rsqrtf(var + BNEPS);
        float sc   = bn_g[t] * inv;
        scl_s[t] = sc;
        sft_s[t] = fmaf(-mean, sc, bn_b[t]);
    }
}

// ---- row-major epilogue (R8/R16, proven): acc -> tr (aliases hs) -> hn ----
__device__ __forceinline__ void conv_epilogue_rm(
    f32x4 acc[8][2], const float bsum[2], const float* __restrict__ msk,
    f16* __restrict__ tr, f16* __restrict__ hnb, float* __restrict__ gstats,
    int r0, int colbase, int l15, int quad, int lane, int t, int slot)
{
    float s[2] = {0.f, 0.f}, ss[2] = {0.f, 0.f};
    #pragma unroll
    for (int nt = 0; nt < 2; ++nt) {
        int col = colbase + nt * 16 + l15;
        #pragma unroll
        for (int mt = 0; mt < 8; ++mt)
            #pragma unroll
            for (int reg = 0; reg < 4; ++reg) {
                int lrow = mt * 16 + quad * 4 + reg;
                float v = (acc[mt][nt][reg] + bsum[nt]) * msk[lrow];
                tr[lrow * HS_STRIDE + col] = (f16)v;
                s[nt] += v; ss[nt] += v * v;
            }
    }
    #pragma unroll
    for (int nt = 0; nt < 2; ++nt) {
        s[nt]  += __shfl_xor(s[nt], 16);  s[nt]  += __shfl_xor(s[nt], 32);
        ss[nt] += __shfl_xor(ss[nt], 16); ss[nt] += __shfl_xor(ss[nt], 32);
    }
    if (lane < 16)
        #pragma unroll
        for (int nt = 0; nt < 2; ++nt) {
            int col = colbase + nt * 16 + lane;
            atomicAdd(&gstats[slot * 2 * H + col],     s[nt]);
            atomicAdd(&gstats[slot * 2 * H + H + col], ss[nt]);
        }
    __syncthreads();
    for (int i = t; i < CNPB * 16; i += 256) {
        int row = i >> 4, g = i & 15;
        *((uint4*)(hnb + (size_t)(r0 + row) * H + g * 8)) =
            *((const uint4*)(tr + row * HS_STRIDE + g * 8));
    }
}

// =================== C-layout epilogue + norm path (small path, proven) ===================
__device__ __forceinline__ void conv_epilogue_c(
    f32x4 acc[8][2], const float bsum[2], const float* __restrict__ msk,
    f16* __restrict__ hnb, float* __restrict__ gstats,
    int tile, int wave, int quad, int lane, int slot)
{
    uint2* out2 = (uint2*)hnb;
    float s[2] = {0.f, 0.f}, ss[2] = {0.f, 0.f};
    #pragma unroll
    for (int nt = 0; nt < 2; ++nt) {
        #pragma unroll
        for (int mt = 0; mt < 8; ++mt) {
            f16 v4[4];
            #pragma unroll
            for (int reg = 0; reg < 4; ++reg) {
                int lrow = mt * 16 + quad * 4 + reg;
                float v = (acc[mt][nt][reg] + bsum[nt]) * msk[lrow];
                v4[reg] = (f16)v;
                s[nt] += v; ss[nt] += v * v;
            }
            size_t chunk = ((size_t)tile * 4 + wave) * 16 + mt * 2 + nt;
            out2[chunk * 64 + lane] = *((const uint2*)v4);
        }
    }
    #pragma unroll
    for (int nt = 0; nt < 2; ++nt) {
        s[nt]  += __shfl_xor(s[nt], 16);  s[nt]  += __shfl_xor(s[nt], 32);
        ss[nt] += __shfl_xor(ss[nt], 16); ss[nt] += __shfl_xor(ss[nt], 32);
    }
    if (lane < 16) {
        int colbase = wave * 32;
        #pragma unroll
        for (int nt = 0; nt < 2; ++nt) {
            int col = colbase + nt * 16 + lane;
            atomicAdd(&gstats[slot * 2 * H + col],     s[nt]);
            atomicAdd(&gstats[slot * 2 * H + H + col], ss[nt]);
        }
    }
}

// ---- layer 0 conv (C-layout variant, small path) ----
__global__ __launch_bounds__(256) void k_conv0f(
    const float* __restrict__ x, const float* __restrict__ ew,
    const float* __restrict__ eb,
    const f16* __restrict__ Wlt, const f16* __restrict__ Wnt,
    const float* __restrict__ bl, const float* __restrict__ bnb,
    const float* __restrict__ mask,
    f16* __restrict__ hnb, float* __restrict__ gstats)
{
    __shared__ __align__(16) f16 hs[(CNPB + 2) * HS_STRIDE];
    __shared__ float ews[3 * H], msk[CNPB];
    const int t = threadIdx.x, lane = t & 63;
    const int l15 = lane & 15, quad = lane >> 4;
    const int wave = t >> 6;
    const int colbase = wave * 32;
    const int r0 = blockIdx.x * CNPB;
    const int batch = r0 >> 13, n0 = r0 & (NN - 1);

    half8 bWl[2][4], bWn[2][4];
    load_bfrags(Wlt, bWl, colbase, l15, quad);
    load_bfrags(Wnt, bWn, colbase, l15, quad);
    float bsum[2];
    #pragma unroll
    for (int nt = 0; nt < 2; ++nt) {
        int col = colbase + nt * 16 + l15;
        bsum[nt] = bl[col] + bnb[col];
    }
    for (int c = t; c < H; c += 256) {
        ews[c] = ew[c]; ews[H + c] = ew[H + c]; ews[2 * H + c] = eb[c];
    }
    if (t < CNPB) msk[t] = mask[r0 + t];
    __syncthreads();

    for (int i = t; i < (CNPB + 2) * 16; i += 256) {
        int row = i >> 4, g = i & 15;
        int n = (n0 + row - 1 + NN) & (NN - 1);
        const float* xp = x + 2 * ((size_t)batch * NN + n);
        float x0 = xp[0], x1 = xp[1];
        f16 o[8];
        #pragma unroll
        for (int e = 0; e < 8; ++e) {
            int c = g * 8 + e;
            o[e] = (f16)fmaf(x1, ews[H + c], fmaf(x0, ews[c], ews[2 * H + c]));
        }
        *((uint4*)(hs + row * HS_STRIDE + g * 8)) = *((const uint4*)o);
    }
    __syncthreads();

    f32x4 acc[8][2];
    conv_mfma8(hs, bWl, bWn, acc, l15, quad);
    conv_epilogue_c(acc, bsum, msk, hnb, gstats,
                    blockIdx.x, wave, quad, lane, blockIdx.x & (NSLOT - 1));
}

// ---- layer 0 conv (row-major tr variant, big path — R16 proven) ----
__global__ __launch_bounds__(256) void k_conv0f_rm(
    const float* __restrict__ x, const float* __restrict__ ew,
    const float* __restrict__ eb,
    const f16* __restrict__ Wlt, const f16* __restrict__ Wnt,
    const float* __restrict__ bl, const float* __restrict__ bnb,
    const float* __restrict__ mask,
    f16* __restrict__ hnb, float* __restrict__ gstats)
{
    __shared__ __align__(16) f16 hs[(CNPB + 2) * HS_STRIDE];
    __shared__ float ews[3 * H], msk[CNPB];
    const int t = threadIdx.x, lane = t & 63;
    const int l15 = lane & 15, quad = lane >> 4;
    const int wave = t >> 6;
    const int colbase = wave * 32;
    const int r0 = blockIdx.x * CNPB;
    const int batch = r0 >> 13, n0 = r0 & (NN - 1);

    half8 bWl[2][4], bWn[2][4];
    load_bfrags(Wlt, bWl, colbase, l15, quad);
    load_bfrags(Wnt, bWn, colbase, l15, quad);
    float bsum[2];
    #pragma unroll
    for (int nt = 0; nt < 2; ++nt) {
        int col = colbase + nt * 16 + l15;
        bsum[nt] = bl[col] + bnb[col];
    }
    for (int c = t; c < H; c += 256) {
        ews[c] = ew[c]; ews[H + c] = ew[H + c]; ews[2 * H + c] = eb[c];
    }
    if (t < CNPB) msk[t] = mask[r0 + t];
    __syncthreads();

    for (int i = t; i < (CNPB + 2) * 16; i += 256) {
        int row = i >> 4, g = i & 15;
        int n = (n0 + row - 1 + NN) & (NN - 1);
        const float* xp = x + 2 * ((size_t)batch * NN + n);
        float x0 = xp[0], x1 = xp[1];
        f16 o[8];
        #pragma unroll
        for (int e = 0; e < 8; ++e) {
            int c = g * 8 + e;
            o[e] = (f16)fmaf(x1, ews[H + c], fmaf(x0, ews[c], ews[2 * H + c]));
        }
        *((uint4*)(hs + row * HS_STRIDE + g * 8)) = *((const uint4*)o);
    }
    __syncthreads();

    f32x4 acc[8][2];
    conv_mfma8(hs, bWl, bWn, acc, l15, quad);
    __syncthreads();   // hs reads done before tr overwrite
    conv_epilogue_rm(acc, bsum, msk, hs, hnb, gstats,
                     r0, colbase, l15, quad, lane, t, blockIdx.x & (NSLOT - 1));
}

// ---- generic conv (layers 1,2; C-layout, small path) ----
__global__ __launch_bounds__(256) void k_conv(
    const f16* __restrict__ hb,
    const f16* __restrict__ Wlt, const f16* __restrict__ Wnt,
    const float* __restrict__ bl, const float* __restrict__ bnb,
    const float* __restrict__ mask,
    f16* __restrict__ hnb, float* __restrict__ gstats)
{
    __shared__ __align__(16) f16 hs[(CNPB + 2) * HS_STRIDE];
    __shared__ float msk[CNPB];
    const int t = threadIdx.x, lane = t & 63;
    const int l15 = lane & 15, quad = lane >> 4;
    const int wave = t >> 6;
    const int colbase = wave * 32;
    const int r0 = blockIdx.x * CNPB;
    const int batch = r0 >> 13, n0 = r0 & (NN - 1);

    half8 bWl[2][4], bWn[2][4];
    load_bfrags(Wlt, bWl, colbase, l15, quad);
    load_bfrags(Wnt, bWn, colbase, l15, quad);
    float bsum[2];
    #pragma unroll
    for (int nt = 0; nt < 2; ++nt) {
        int col = colbase + nt * 16 + l15;
        bsum[nt] = bl[col] + bnb[col];
    }
    if (t < CNPB) msk[t] = mask[r0 + t];

    for (int i = t; i < (CNPB + 2) * 16; i += 256) {
        int row = i >> 4, g = i & 15;
        int n = (n0 + row - 1 + NN) & (NN - 1);
        *((uint4*)(hs + row * HS_STRIDE + g * 8)) =
            *((const uint4*)(hb + ((size_t)(batch * NN + n)) * H + g * 8));
    }
    __syncthreads();

    f32x4 acc[8][2];
    conv_mfma8(hs, bWl, bWn, acc, l15, quad);
    conv_epilogue_c(acc, bsum, msk, hnb, gstats,
                    blockIdx.x, wave, quad, lane, blockIdx.x & (NSLOT - 1));
}

// ---- fused conv layer 1 (big path, R16 proven): h1 = affine(x)+relu(BN0(hn0));
//      BN0 per block; HB written during staging; tr epilogue ----
__global__ __launch_bounds__(256, 3) void k_cn1(
    const float* __restrict__ x, const float* __restrict__ ew,
    const float* __restrict__ eb, const f16* __restrict__ hnA,
    const float* __restrict__ gst0, const float* __restrict__ bn_g,
    const float* __restrict__ bn_b,
    const f16* __restrict__ Wlt, const f16* __restrict__ Wnt,
    const float* __restrict__ bl, const float* __restrict__ bnb,
    const float* __restrict__ mask,
    f16* __restrict__ HB, f16* __restrict__ hnB, float* __restrict__ gst1)
{
    __shared__ __align__(16) f16 hs[(CNPB + 2) * HS_STRIDE];
    __shared__ float ews[3 * H], sclA[H], sftA[H], msk[CNPB];
    const int t = threadIdx.x, lane = t & 63;
    const int l15 = lane & 15, quad = lane >> 4;
    const int wave = t >> 6;
    const int colbase = wave * 32;
    const int r0 = blockIdx.x * CNPB;
    const int batch = r0 >> 13, n0 = r0 & (NN - 1);

    half8 bWl[2][4], bWn[2][4];
    load_bfrags(Wlt, bWl, colbase, l15, quad);
    load_bfrags(Wnt, bWn, colbase, l15, quad);
    float bsum[2];
    #pragma unroll
    for (int nt = 0; nt < 2; ++nt) {
        int col = colbase + nt * 16 + l15;
        bsum[nt] = bl[col] + bnb[col];
    }
    bn_finalize(gst0, bn_g, bn_b, t, sclA, sftA);
    for (int c = t; c < H; c += 256) {
        ews[c] = ew[c]; ews[H + c] = ew[H + c]; ews[2 * H + c] = eb[c];
    }
    if (t < CNPB) msk[t] = mask[r0 + t];
    __syncthreads();

    for (int i = t; i < (CNPB + 2) * 16; i += 256) {
        int row = i >> 4, g = i & 15;
        int n = (n0 + row - 1 + NN) & (NN - 1);
        size_t base = (size_t)batch * NN + n;
        const float* xp = x + 2 * base;
        float x0 = xp[0], x1 = xp[1];
        uint4 pa = *((const uint4*)(hnA + base * H + g * 8));
        float va[8];
        unpackh8(pa, va);
        f16 o[8];
        #pragma unroll
        for (int e = 0; e < 8; ++e) {
            int c = g * 8 + e;
            float h0 = fmaf(x1, ews[H + c], fmaf(x0, ews[c], ews[2 * H + c]));
            o[e] = (f16)(h0 + fmaxf(fmaf(va[e], sclA[c], sftA[c]), 0.f));
        }
        *((uint4*)(hs + row * HS_STRIDE + g * 8)) = *((const uint4*)o);
        if (row >= 1 && row <= CNPB)   // h1 tile rows -> HB (own-row, exact once)
            *((uint4*)(HB + base * H + g * 8)) = *((const uint4*)o);
    }
    __syncthreads();

    f32x4 acc[8][2];
    conv_mfma8(hs, bWl, bWn, acc, l15, quad);
    __syncthreads();   // all hs reads done before tr overwrite

    conv_epilogue_rm(acc, bsum, msk, hs, hnB, gst1,
                     r0, colbase, l15, quad, lane, t, blockIdx.x & (NSLOT - 1));
}

// ---- fused conv layer 2 (big path, R16 proven): h2 = h1 + relu(BN1(hn1)) ----
__global__ __launch_bounds__(256) void k_cn2(
    const f16* __restrict__ HB, const f16* __restrict__ hnB,
    const float* __restrict__ gst1, const float* __restrict__ bn_g,
    const float* __restrict__ bn_b,
    const f16* __restrict__ Wlt, const f16* __restrict__ Wnt,
    const float* __restrict__ bl, const float* __restrict__ bnb,
    const float* __restrict__ mask,
    f16* __restrict__ hnA, float* __restrict__ gst2)
{
    __shared__ __align__(16) f16 hs[(CNPB + 2) * HS_STRIDE];
    __shared__ float sclA[H], sftA[H], msk[CNPB];
    const int t = threadIdx.x, lane = t & 63;
    const int l15 = lane & 15, quad = lane >> 4;
    const int wave = t >> 6;
    const int colbase = wave * 32;
    const int r0 = blockIdx.x * CNPB;
    const int batch = r0 >> 13, n0 = r0 & (NN - 1);

    half8 bWl[2][4], bWn[2][4];
    load_bfrags(Wlt, bWl, colbase, l15, quad);
    load_bfrags(Wnt, bWn, colbase, l15, quad);
    float bsum[2];
    #pragma unroll
    for (int nt = 0; nt < 2; ++nt) {
        int col = colbase + nt * 16 + l15;
        bsum[nt] = bl[col] + bnb[col];
    }
    bn_finalize(gst1, bn_g, bn_b, t, sclA, sftA);
    if (t < CNPB) msk[t] = mask[r0 + t];
    __syncthreads();

    for (int i = t; i < (CNPB + 2) * 16; i += 256) {
        int row = i >> 4, g = i & 15;
        int n = (n0 + row - 1 + NN) & (NN - 1);
        size_t off = ((size_t)batch * NN + n) * H + g * 8;
        uint4 ph = *((const uint4*)(HB + off));
        uint4 pn = *((const uint4*)(hnB + off));
        float vh[8], vn[8];
        unpackh8(ph, vh);
        unpackh8(pn, vn);
        f16 o[8];
        #pragma unroll
        for (int e = 0; e < 8; ++e) {
            int c = g * 8 + e;
            o[e] = (f16)(vh[e] + fmaxf(fmaf(vn[e], sclA[c], sftA[c]), 0.f));
        }
        *((uint4*)(hs + row * HS_STRIDE + g * 8)) = *((const uint4*)o);
    }
    __syncthreads();

    f32x4 acc[8][2];
    conv_mfma8(hs, bWl, bWn, acc, l15, quad);
    __syncthreads();

    conv_epilogue_rm(acc, bsum, msk, hs, hnA, gst2,
                     r0, colbase, l15, quad, lane, t, blockIdx.x & (NSLOT - 1));
}

// =================== small-path norm kernels (R13, proven) ===================
__device__ __forceinline__ void norm_ingest(
    const f16* __restrict__ hnb, int blk, int t,
    const float* __restrict__ scl_s, const float* __restrict__ sft_s,
    f16* __restrict__ g)
{
    const uint4* src = (const uint4*)hnb + (size_t)blk * 2048;
    for (int i = t; i < 2048; i += 256) {
        uint4 pk = src[i];
        int chunk = i >> 5;
        int L     = (i & 31) * 2;
        int ntv   = chunk & 1;
        int mtv   = (chunk >> 1) & 7;
        int wv    = chunk >> 4;
        int c0    = wv * 32 + ntv * 16 + (L & 15);
        int row0  = mtv * 16 + (L >> 4) * 4;
        float vv[8];
        unpackh8(pk, vv);
        #pragma unroll
        for (int e = 0; e < 8; ++e) {
            int cc = c0 + (e >> 2);
            int rr = row0 + (e & 3);
            float q = fmaxf(fmaf(vv[e], scl_s[cc], sft_s[cc]), 0.f);
            g[rr * HS_STRIDE + cc] = (f16)q;
        }
    }
}

__global__ __launch_bounds__(256) void k_norm0(
    const float* __restrict__ x, const float* __restrict__ ew,
    const float* __restrict__ eb, const f16* __restrict__ hnb,
    const float* __restrict__ gstats, const float* __restrict__ bn_g,
    const float* __restrict__ bn_b, f16* __restrict__ hb)
{
    __shared__ __align__(16) f16 g[CNPB * HS_STRIDE];
    __shared__ float scl_s[H], sft_s[H], ews[3 * H];
    const int t = threadIdx.x;
    const int blk = blockIdx.x;
    const size_t r0 = (size_t)blk * CNPB;

    bn_finalize(gstats, bn_g, bn_b, t, scl_s, sft_s);
    if (t < H) { ews[t] = ew[t]; ews[H + t] = ew[H + t]; ews[2 * H + t] = eb[t]; }
    __syncthreads();

    norm_ingest(hnb, blk, t, scl_s, sft_s, g);
    __syncthreads();

    for (int i = t; i < 2048; i += 256) {
        int row = i >> 4, gg = i & 15;
        size_t grow = r0 + row;
        float x0 = x[2 * grow], x1 = x[2 * grow + 1];
        uint4 pg = *((const uint4*)(g + row * HS_STRIDE + gg * 8));
        float vg[8], vh[8];
        unpackh8(pg, vg);
        #pragma unroll
        for (int e = 0; e < 8; ++e) {
            int c = gg * 8 + e;
            float h0 = fmaf(x1, ews[H + c], fmaf(x0, ews[c], ews[2 * H + c]));
            vh[e] = h0 + vg[e];
        }
        *((uint4*)(hb + grow * H + gg * 8)) = packh8(vh);
    }
}

__global__ __launch_bounds__(256) void k_norm(
    const f16* __restrict__ hnb, const float* __restrict__ gstats,
    const float* __restrict__ bn_g, const float* __restrict__ bn_b,
    f16* __restrict__ hb)
{
    __shared__ __align__(16) f16 g[CNPB * HS_STRIDE];
    __shared__ float scl_s[H], sft_s[H];
    const int t = threadIdx.x;
    const int blk = blockIdx.x;
    const size_t r0 = (size_t)blk * CNPB;

    bn_finalize(gstats, bn_g, bn_b, t, scl_s, sft_s);
    __syncthreads();

    norm_ingest(hnb, blk, t, scl_s, sft_s, g);
    __syncthreads();

    for (int i = t; i < 2048; i += 256) {
        int row = i >> 4, gg = i & 15;
        size_t grow = r0 + row;
        uint4 ph = *((const uint4*)(hb + grow * H + gg * 8));
        uint4 pg = *((const uint4*)(g + row * HS_STRIDE + gg * 8));
        float vh[8], vg[8];
        unpackh8(ph, vh);
        unpackh8(pg, vg);
        #pragma unroll
        for (int e = 0; e < 8; ++e) vh[e] += vg[e];
        *((uint4*)(hb + grow * H + gg * 8)) = packh8(vh);
    }
}

// ---- MFMA head (small path, R13) ----
__global__ __launch_bounds__(256) void k_head(
    const f16* __restrict__ hb, const float* __restrict__ W1,
    const float* __restrict__ b1, const float* __restrict__ W2,
    const float* __restrict__ b2, const float* __restrict__ mask,
    float* __restrict__ out)
{
    __shared__ f16 hs [64 * HS_STRIDE];
    __shared__ f16 w1t[64 * HS_STRIDE];
    const int t    = threadIdx.x;
    const int wave = t >> 6;
    const int lane = t & 63;
    const int l15  = lane & 15;
    const int quad = lane >> 4;
    const int r0   = blockIdx.x * HNPB;

    for (int i = t; i < 64 * 16; i += 256) {
        int row = i >> 4, g = i & 15;
        *((uint4*)(hs + row * HS_STRIDE + g * 8)) =
            *((const uint4*)(hb + (size_t)(r0 + row) * H + g * 8));
    }
    for (int i = t; i < H * 64; i += 256) {
        int k = i >> 6, n = i & 63;
        w1t[n * HS_STRIDE + k] = (f16)W1[i];
    }
    __syncthreads();

    f32x4 acc[4];
    #pragma unroll
    for (int nt = 0; nt < 4; ++nt) acc[nt] = (f32x4){0.f, 0.f, 0.f, 0.f};
    #pragma unroll
    for (int ks = 0; ks < 4; ++ks) {
        half8 a = *((const half8*)(hs + (wave * 16 + l15) * HS_STRIDE + ks * 32 + quad * 8));
        #pragma unroll
        for (int nt = 0; nt < 4; ++nt) {
            half8 b = *((const half8*)(w1t + (nt * 16 + l15) * HS_STRIDE + ks * 32 + quad * 8));
            acc[nt] = __builtin_amdgcn_mfma_f32_16x16x32_f16(a, b, acc[nt], 0, 0, 0);
        }
    }

    float p0[4] = {0,0,0,0}, p1[4] = {0,0,0,0};
    #pragma unroll
    for (int nt = 0; nt < 4; ++nt) {
        int col = nt * 16 + l15;
        float bb = b1[col];
        float wa = W2[2 * col], wb = W2[2 * col + 1];
        #pragma unroll
        for (int reg = 0; reg < 4; ++reg) {
            float v = fmaxf(acc[nt][reg] + bb, 0.f);
            p0[reg] = fmaf(v, wa, p0[reg]);
            p1[reg] = fmaf(v, wb, p1[reg]);
        }
    }
    #pragma unroll
    for (int reg = 0; reg < 4; ++reg) {
        p0[reg] += __shfl_xor(p0[reg], 1); p0[reg] += __shfl_xor(p0[reg], 2);
        p0[reg] += __shfl_xor(p0[reg], 4); p0[reg] += __shfl_xor(p0[reg], 8);
        p1[reg] += __shfl_xor(p1[reg], 1); p1[reg] += __shfl_xor(p1[reg], 2);
        p1[reg] += __shfl_xor(p1[reg], 4); p1[reg] += __shfl_xor(p1[reg], 8);
    }
    if (l15 == 0) {
        #pragma unroll
        for (int reg = 0; reg < 4; ++reg) {
            int gr = r0 + wave * 16 + quad * 4 + reg;
            float m = mask[gr];
            float2 o;
            o.x = (p0[reg] + b2[0]) * m;
            o.y = (p1[reg] + b2[1]) * m;
            *((float2*)(out + 2 * gr)) = o;
        }
    }
}

// ---- fused head (big path): h3 chain; BN per block from WS gstats;
//      w1t staged from pre-transposed fp16 W1t (uint4 copies, FULL 128-k rows) ----
// Invariant: writes `out` (d_out) and reads NOTHING from d_out.
__global__ __launch_bounds__(256) void k_head_f(
    const f16* __restrict__ HB, const f16* __restrict__ hn1,
    const f16* __restrict__ hn2,
    const float* __restrict__ gst1, const float* __restrict__ gst2,
    const float* __restrict__ bn_g, const float* __restrict__ bn_b,
    const f16* __restrict__ W1t, const float* __restrict__ b1,
    const float* __restrict__ W2, const float* __restrict__ b2,
    const float* __restrict__ mask, float* __restrict__ out)
{
    __shared__ f16 hs [64 * HS_STRIDE];
    __shared__ f16 w1t[64 * HS_STRIDE];
    __shared__ float scl1[H], sft1[H], scl2[H], sft2[H];
    const int t    = threadIdx.x;
    const int wave = t >> 6;
    const int lane = t & 63;
    const int l15  = lane & 15;
    const int quad = lane >> 4;
    const int r0   = blockIdx.x * HNPB;

    bn_finalize(gst1, bn_g,     bn_b,     t, scl1, sft1);
    bn_finalize(gst2, bn_g + H, bn_b + H, t, scl2, sft2);
    // W1t rows are 128 fp16 = 16 uint4 groups; cover ALL of them (R18 bug: only 8).
    for (int i = t; i < 64 * 16; i += 256) {
        int n = i >> 4, g = i & 15;
        *((uint4*)(w1t + n * HS_STRIDE + g * 8)) =
            *((const uint4*)(W1t + n * 128 + g * 8));
    }
    __syncthreads();   // scl + w1t ready

    for (int i = t; i < 64 * 16; i += 256) {
        int row = i >> 4, g = i & 15;
        size_t off = (size_t)(r0 + row) * H + g * 8;
        uint4 ph = *((const uint4*)(HB + off));
        uint4 p1v = *((const uint4*)(hn1 + off));
        uint4 p2v = *((const uint4*)(hn2 + off));
        float vh[8], v1[8], v2[8];
        unpackh8(ph, vh);
        unpackh8(p1v, v1);
        unpackh8(p2v, v2);
        f16 o[8];
        #pragma unroll
        for (int e = 0; e < 8; ++e) {
            int c = g * 8 + e;
            float h2 = vh[e] + fmaxf(fmaf(v1[e], scl1[c], sft1[c]), 0.f);
            o[e] = (f16)(h2 + fmaxf(fmaf(v2[e], scl2[c], sft2[c]), 0.f));
        }
        *((uint4*)(hs + row * HS_STRIDE + g * 8)) = *((const uint4*)o);
    }
    __syncthreads();

    f32x4 acc[4];
    #pragma unroll
    for (int nt = 0; nt < 4; ++nt) acc[nt] = (f32x4){0.f, 0.f, 0.f, 0.f};
    #pragma unroll
    for (int ks = 0; ks < 4; ++ks) {
        half8 a = *((const half8*)(hs + (wave * 16 + l15) * HS_STRIDE + ks * 32 + quad * 8));
        #pragma unroll
        for (int nt = 0; nt < 4; ++nt) {
            half8 b = *((const half8*)(w1t + (nt * 16 + l15) * HS_STRIDE + ks * 32 + quad * 8));
            acc[nt] = __builtin_amdgcn_mfma_f32_16x16x32_f16(a, b, acc[nt], 0, 0, 0);
        }
    }

    float p0[4] = {0,0,0,0}, p1a[4] = {0,0,0,0};
    #pragma unroll
    for (int nt = 0; nt < 4; ++nt) {
        int col = nt * 16 + l15;
        float bb = b1[col];
        float wa = W2[2 * col], wb = W2[2 * col + 1];
        #pragma unroll
        for (int reg = 0; reg < 4; ++reg) {
            float v = fmaxf(acc[nt][reg] + bb, 0.f);
            p0[reg]  = fmaf(v, wa, p0[reg]);
            p1a[reg] = fmaf(v, wb, p1a[reg]);
        }
    }
    #pragma unroll
    for (int reg = 0; reg < 4; ++reg) {
        p0[reg]  += __shfl_xor(p0[reg], 1);  p0[reg]  += __shfl_xor(p0[reg], 2);
        p0[reg]  += __shfl_xor(p0[reg], 4);  p0[reg]  += __shfl_xor(p0[reg], 8);
        p1a[reg] += __shfl_xor(p1a[reg], 1); p1a[reg] += __shfl_xor(p1a[reg], 2);
        p1a[reg] += __shfl_xor(p1a[reg], 4); p1a[reg] += __shfl_xor(p1a[reg], 8);
    }
    if (l15 == 0) {
        #pragma unroll
        for (int reg = 0; reg < 4; ++reg) {
            int gr = r0 + wave * 16 + quad * 4 + reg;
            float m = mask[gr];
            float2 o;
            o.x = (p0[reg]  + b2[0]) * m;
            o.y = (p1a[reg] + b2[1]) * m;
            *((float2*)(out + 2 * gr)) = o;
        }
    }
}

extern "C" void kernel_launch(void* const* d_in, const int* in_sizes, int n_in,
                              void* d_out, int out_size, void* d_ws, size_t ws_size,
                              hipStream_t stream)
{
    const float* x     = (const float*)d_in[0];
    const float* mask  = (const float*)d_in[1];
    const float* emb_w = (const float*)d_in[2];
    const float* emb_b = (const float*)d_in[3];
    const float* lin_w = (const float*)d_in[4];
    const float* lin_b = (const float*)d_in[5];
    const float* nb_w  = (const float*)d_in[6];
    const float* nb_b  = (const float*)d_in[7];
    const float* bn_g  = (const float*)d_in[8];
    const float* bn_b  = (const float*)d_in[9];
    const float* o1w   = (const float*)d_in[10];
    const float* o1b   = (const float*)d_in[11];
    const float* o2w   = (const float*)d_in[12];
    const float* o2b   = (const float*)d_in[13];
    float* out = (float*)d_out;

    const size_t BUF = (size_t)RTOT * H * 2;   // 64 MiB per f16 buffer
    const size_t GSTB = NLAYER * NSLOT * 2 * H * sizeof(float);  // 48 KiB
    char* ws = (char*)d_ws;

    // d_out holds ONLY Wlt/Wnt (read by conv kernels that never write `out`).
    f16* Wlt = (f16*)((float*)d_out + 65536);    // 3*128*128 fp16
    f16* Wnt = Wlt + NLAYER * H * H;

    bool big = (ws_size >= 3 * BUF + 65536);

    if (big) {
        // ---- big path: 3 data buffers + gstats (48K) + W1t (16K) in WS ----
        f16* HB  = (f16*)ws;
        f16* hnA = (f16*)(ws + BUF);
        f16* hnB = (f16*)(ws + 2 * BUF);
        float* gstw = (float*)(ws + 3 * BUF);           // 48 KiB
        f16* W1t16 = (f16*)(ws + 3 * BUF + GSTB);       // 16 KiB

        k_prep<<<416, 256, 0, stream>>>(lin_w, nb_w, o1w, Wlt, Wnt, W1t16);
        hipMemsetAsync(gstw, 0, GSTB, stream);

        k_conv0f_rm<<<NTILEC, 256, 0, stream>>>(
            x, emb_w, emb_b, Wlt, Wnt, lin_b, nb_b, mask, hnA, gstw);
        k_cn1<<<NTILEC, 256, 0, stream>>>(
            x, emb_w, emb_b, hnA, gstw, bn_g, bn_b, Wlt + H * H, Wnt + H * H,
            lin_b + H, nb_b + H, mask, HB, hnB, gstw + NSLOT * 2 * H);
        k_cn2<<<NTILEC, 256, 0, stream>>>(
            HB, hnB, gstw + NSLOT * 2 * H, bn_g + H, bn_b + H,
            Wlt + 2 * H * H, Wnt + 2 * H * H,
            lin_b + 2 * H, nb_b + 2 * H, mask, hnA, gstw + 2 * NSLOT * 2 * H);
        k_head_f<<<RTOT / HNPB, 256, 0, stream>>>(
            HB, hnB, hnA, gstw + NSLOT * 2 * H, gstw + 2 * NSLOT * 2 * H,
            bn_g + H, bn_b + H, W1t16, o1b, o2w, o2b, mask, out);
    } else {
        // ---- small path: exact R13 pipeline (proven, 343.6 us) ----
        float* gst = (float*)d_out;   // safe here: k_head reads no d_out scratch
        f16* hb  = (f16*)ws;
        f16* hnb = (f16*)(ws + BUF);

        k_prep<<<384, 256, 0, stream>>>(lin_w, nb_w, o1w, Wlt, Wnt, (f16*)nullptr);
        hipMemsetAsync(gst, 0, GSTB, stream);

        k_conv0f<<<NTILEC, 256, 0, stream>>>(
            x, emb_w, emb_b, Wlt, Wnt, lin_b, nb_b, mask, hnb, gst);
        k_norm0<<<NTILEC, 256, 0, stream>>>(
            x, emb_w, emb_b, hnb, gst, bn_g, bn_b, hb);
        for (int i = 1; i < NLAYER; ++i) {
            k_conv<<<NTILEC, 256, 0, stream>>>(
                hb, Wlt + i * H * H, Wnt + i * H * H,
                lin_b + i * H, nb_b + i * H, mask,
                hnb, gst + i * NSLOT * 2 * H);
            k_norm<<<NTILEC, 256, 0, stream>>>(
                hnb, gst + i * NSLOT * 2 * H, bn_g + i * H, bn_b + i * H, hb);
        }
        k_head<<<RTOT / HNPB, 256, 0, stream>>>(hb, o1w, o1b, o2w, o2b, mask, out);
    }
}